// Round 4
// baseline (316.711 us; speedup 1.0000x reference)
//
#include <hip/hip_runtime.h>
#include <hip/hip_bf16.h>

// Problem constants (from reference)
#define B_    8
#define C_    128
#define H_    64
#define W_    64
#define COUT_ 128
#define K_    3
#define K2_   9
#define JOFF_ 18            // 2*K*K offset channels
#define HW_   (H_*W_)       // 4096
#define CK_   (C_*K2_)      // 1152

typedef short  short8 __attribute__((ext_vector_type(8)));   // 8 bf16 in 4 VGPR
typedef float  f32x4  __attribute__((ext_vector_type(4)));

__device__ __forceinline__ ushort f2bf(float f) {
    __hip_bfloat16 h = __float2bfloat16(f);
    return *reinterpret_cast<ushort*>(&h);
}

// ---------------------------------------------------------------------------
// Kernel A: offset conv (3x3, pad 1, stride 1) + bias.
// Block = one (b,row): 4 waves = 4 channel-quarters, each thread keeps all
// 18 output-channel accumulators in VGPRs (x loaded once, reused 18x).
// ---------------------------------------------------------------------------
__global__ __launch_bounds__(256) void offset_conv_kernel(
    const float* __restrict__ x, const float* __restrict__ w_off,
    const float* __restrict__ b_off, float* __restrict__ offs)
{
    __shared__ float red[3][JOFF_][64];      // 13.8 KB partials from waves 1..3

    const int bid  = blockIdx.x;             // 512 blocks
    const int nbid = ((bid & 7) << 6) + (bid >> 3);   // XCD chunking: 1 image/XCD
    const int b    = nbid >> 6;
    const int row  = nbid & 63;

    const int t  = threadIdx.x;
    const int s  = t & 63;                   // position in row
    const int wv = t >> 6;                   // channel quarter 0..3
    const int wvu = __builtin_amdgcn_readfirstlane(wv);

    // 9-tap masks + clamped flat indices at (row, s)
    float m[K2_]; int idx[K2_];
#pragma unroll
    for (int ky = 0; ky < 3; ++ky) {
#pragma unroll
        for (int kx = 0; kx < 3; ++kx) {
            int y  = row - 1 + ky;
            int xx = s  - 1 + kx;
            bool v = (y >= 0) & (y < H_) & (xx >= 0) & (xx < W_);
            int yc = min(max(y, 0), H_ - 1);
            int xc = min(max(xx, 0), W_ - 1);
            m[ky*3+kx]   = v ? 1.0f : 0.0f;
            idx[ky*3+kx] = yc * W_ + xc;
        }
    }

    const float* xb = x + ((size_t)b << 19) + ((size_t)wvu << 17);  // b,c-quarter
    const float* wb = w_off + wvu * 32 * K2_;                       // uniform base

    float acc[JOFF_];
#pragma unroll
    for (int j = 0; j < JOFF_; ++j) acc[j] = 0.f;

    for (int c = 0; c < 32; ++c) {
        const float* xc = xb + (c << 12);
        float xv[K2_];
#pragma unroll
        for (int k = 0; k < K2_; ++k) xv[k] = xc[idx[k]] * m[k];
#pragma unroll
        for (int k = 0; k < K2_; ++k) {
            const float* wp = wb + c * K2_ + k;
#pragma unroll
            for (int j = 0; j < JOFF_; ++j)
                acc[j] = fmaf(wp[(size_t)j * CK_], xv[k], acc[j]);
        }
    }

    if (wv > 0) {
#pragma unroll
        for (int j = 0; j < JOFF_; ++j) red[wv-1][j][s] = acc[j];
    }
    __syncthreads();
    if (wv == 0) {
#pragma unroll
        for (int j = 0; j < JOFF_; ++j) {
            float r = acc[j] + red[0][j][s] + red[1][j][s] + red[2][j][s] + b_off[j];
            offs[((size_t)(b * JOFF_ + j) << 12) + (row << 6) + s] = r;
        }
    }
}

// ---------------------------------------------------------------------------
// Kernel T: w_def -> wt[k][o][c] bf16 (tap-major, linear).
// ---------------------------------------------------------------------------
__global__ __launch_bounds__(256) void transpose_wdef_kernel(
    const float* __restrict__ w_def, ushort* __restrict__ wt)
{
    int t = blockIdx.x * 256 + threadIdx.x;
    if (t >= K2_ * COUT_ * C_) return;
    int c = t & 127;
    int o = (t >> 7) & 127;
    int k = t >> 14;
    float v = w_def[((size_t)o * C_ + c) * K2_ + k];
    wt[((size_t)k * COUT_ + o) * C_ + c] = f2bf(v);
}

// ---------------------------------------------------------------------------
// Kernel B: fused deformable gather + MFMA GEMM.
// Block = 256 threads (4 waves, 2x2 wave grid), 128 out channels x 64
// positions (one image row). Per tap: gather -> swizzled sB, barrier, then
// MFMA with A fragments loaded per-kc from global (L2-resident wt) so only
// 16 VGPRs of A are live at a time (round-3 version spilled 64).
// Out stores are nontemporal: keeps the per-XCD L2 for x/wt/offs.
// ---------------------------------------------------------------------------
__global__ __launch_bounds__(256, 4) void deform_mfma_kernel(
    const float* __restrict__ x, const float* __restrict__ offs,
    const ushort* __restrict__ wt, float* __restrict__ out)
{
    __shared__ ushort sB[64][C_];            // 16 KB, XOR-swizzled
    __shared__ float  s_off[JOFF_][64];      // 4.6 KB raw offsets for this row

    const int bid  = blockIdx.x;             // 512 blocks
    const int nbid = ((bid & 7) << 6) + (bid >> 3);   // XCD chunking: 1 image/XCD
    const int s0   = nbid << 6;
    const int b    = s0 >> 12;
    const int hw0  = s0 & (HW_ - 1);
    const int ho   = hw0 >> 6;

    const int t    = threadIdx.x;
    const int wid  = t >> 6, lane = t & 63;
    const int wm   = wid >> 1, wn = wid & 1; // 2x2 wave grid: 64(M) x 32(N)
    const int sg   = lane;                   // gather position = lane
    const int cq   = wid;                    // gather channel quarter
    const float* xb = x + ((size_t)b << 19);

    // Phase 0: cache this row's 18 offset planes in LDS (coalesced)
    for (int e = t; e < JOFF_ * 64; e += 256) {
        int j = e >> 6, s = e & 63;
        s_off[j][s] = offs[((size_t)(b * JOFF_ + j) << 12) + hw0 + s];
    }
    __syncthreads();

    f32x4 acc[4][2] = {};
    const int swz  = (sg & 7) << 3;
    const int arow = lane & 15;
    const int akk  = (lane >> 4) << 3;

    for (int k = 0; k < K2_; ++k) {
        // ---- bilinear setup for this lane's position (registers only)
        float dy = s_off[2*k    ][sg];
        float dx = s_off[2*k + 1][sg];
        float py = (float)(ho - 1 + k/3) + dy;
        float px = (float)(sg - 1 + k%3) + dx;
        float y0f = floorf(py), x0f = floorf(px);
        float wy = py - y0f,    wx = px - x0f;
        int y0 = (int)y0f, x0 = (int)x0f;
        int y1 = y0 + 1,   x1 = x0 + 1;
        float vy0 = (y0 >= 0 && y0 < H_) ? 1.f : 0.f;
        float vy1 = (y1 >= 0 && y1 < H_) ? 1.f : 0.f;
        float vx0 = (x0 >= 0 && x0 < W_) ? 1.f : 0.f;
        float vx1 = (x1 >= 0 && x1 < W_) ? 1.f : 0.f;
        int y0c = min(max(y0, 0), H_-1), y1c = min(max(y1, 0), H_-1);
        int x0c = min(max(x0, 0), W_-1), x1c = min(max(x1, 0), W_-1);
        float wr[4]; int ixr[4];
        wr[0] = (1.f-wy)*(1.f-wx)*vy0*vx0;  ixr[0] = y0c*W_ + x0c;
        wr[1] = (1.f-wy)*wx      *vy0*vx1;  ixr[1] = y0c*W_ + x1c;
        wr[2] = wy      *(1.f-wx)*vy1*vx0;  ixr[2] = y1c*W_ + x0c;
        wr[3] = wy      *wx      *vy1*vx1;  ixr[3] = y1c*W_ + x1c;

        // ---- gather B tile: valT[s][c] bf16, swizzled writes
#pragma unroll
        for (int i = 0; i < 16; ++i) {
            int c0 = (cq + i*4) * 2;                 // even channels 0..126
            const float* xc0 = xb + ((size_t)c0 << 12);
            const float* xc1 = xc0 + HW_;
            float v0 = 0.f, v1 = 0.f;
#pragma unroll
            for (int r = 0; r < 4; ++r) {
                v0 = fmaf(wr[r], xc0[ixr[r]], v0);
                v1 = fmaf(wr[r], xc1[ixr[r]], v1);
            }
            uint pk = (uint)f2bf(v0) | ((uint)f2bf(v1) << 16);
            *reinterpret_cast<uint*>(&sB[sg][c0 ^ swz]) = pk;
        }
        __syncthreads();

        // ---- MFMA: 4 chunks of K=32 channels; A fragments loaded per chunk
        const ushort* wk = wt + (size_t)k * (COUT_ * C_);
#pragma unroll
        for (int kc = 0; kc < 4; ++kc) {
            short8 aF[4], bF[2];
#pragma unroll
            for (int mi = 0; mi < 4; ++mi)
                aF[mi] = *reinterpret_cast<const short8*>(
                    wk + (wm*64 + mi*16 + arow) * C_ + kc*32 + akk);
#pragma unroll
            for (int ni = 0; ni < 2; ++ni) {
                int srow = wn*32 + ni*16 + (lane & 15);
                bF[ni] = *reinterpret_cast<const short8*>(
                    &sB[srow][(kc*32 + akk) ^ ((srow & 7) << 3)]);
            }
#pragma unroll
            for (int mi = 0; mi < 4; ++mi)
#pragma unroll
                for (int ni = 0; ni < 2; ++ni)
                    acc[mi][ni] = __builtin_amdgcn_mfma_f32_16x16x32_bf16(
                        aF[mi], bF[ni], acc[mi][ni], 0, 0, 0);
        }
        __syncthreads();
    }

    // ---- epilogue: C/D layout col=lane&15, row=(lane>>4)*4+reg; nt stores
#pragma unroll
    for (int mi = 0; mi < 4; ++mi) {
#pragma unroll
        for (int ni = 0; ni < 2; ++ni) {
#pragma unroll
            for (int r = 0; r < 4; ++r) {
                int o = wm*64 + mi*16 + ((lane >> 4) * 4 + r);
                int s = wn*32 + ni*16 + (lane & 15);
                __builtin_nontemporal_store(acc[mi][ni][r],
                    &out[(((size_t)(b*COUT_ + o)) << 12) + hw0 + s]);
            }
        }
    }
}

// ---------------------------------------------------------------------------
extern "C" void kernel_launch(void* const* d_in, const int* in_sizes, int n_in,
                              void* d_out, int out_size, void* d_ws, size_t ws_size,
                              hipStream_t stream) {
    const float* x     = (const float*)d_in[0];
    const float* w_off = (const float*)d_in[1];
    const float* b_off = (const float*)d_in[2];
    const float* w_def = (const float*)d_in[3];
    float* out  = (float*)d_out;

    float*  offs = (float*)d_ws;                                    // 2,359,296 B
    ushort* wt   = (ushort*)((char*)d_ws + (size_t)B_*JOFF_*HW_*4); //   294,912 B

    // Kernel A: offsets (one block per (b,row))
    {
        offset_conv_kernel<<<B_ * H_, 256, 0, stream>>>(x, w_off, b_off, offs);
    }
    // Kernel T: w_def -> bf16 tap-major
    {
        int total  = K2_ * COUT_ * C_;
        int blocks = (total + 255) / 256;
        transpose_wdef_kernel<<<blocks, 256, 0, stream>>>(w_def, wt);
    }
    // Kernel B: fused gather + MFMA GEMM
    {
        int blocks = (B_ * HW_) / 64;   // 512
        deform_mfma_kernel<<<blocks, 256, 0, stream>>>(x, offs, wt, out);
    }
}

// Round 5
// 151.118 us; speedup vs baseline: 2.0958x; 2.0958x over previous
//
#include <hip/hip_runtime.h>
#include <hip/hip_bf16.h>

// Problem constants (from reference)
#define B_    8
#define C_    128
#define H_    64
#define W_    64
#define COUT_ 128
#define K_    3
#define K2_   9
#define JOFF_ 18            // 2*K*K offset channels
#define HW_   (H_*W_)       // 4096
#define CK_   (C_*K2_)      // 1152

typedef short  short8 __attribute__((ext_vector_type(8)));   // 8 bf16 in 4 VGPR
typedef float  f32x4  __attribute__((ext_vector_type(4)));

__device__ __forceinline__ ushort f2bf(float f) {
    __hip_bfloat16 h = __float2bfloat16(f);
    return *reinterpret_cast<ushort*>(&h);
}

__device__ __forceinline__ void gl2lds16(const void* g, void* l) {
    __builtin_amdgcn_global_load_lds(
        (const __attribute__((address_space(1))) void*)g,
        (__attribute__((address_space(3))) void*)l, 16, 0, 0);
}

// ---------------------------------------------------------------------------
// Kernel A: offset conv (3x3, pad 1, stride 1) + bias.
// Block = one (b,row): 4 waves = 4 channel-quarters, each thread keeps all
// 18 output-channel accumulators in VGPRs.
// ---------------------------------------------------------------------------
__global__ __launch_bounds__(256) void offset_conv_kernel(
    const float* __restrict__ x, const float* __restrict__ w_off,
    const float* __restrict__ b_off, float* __restrict__ offs)
{
    __shared__ float red[3][JOFF_][64];      // partials from waves 1..3

    const int bid  = blockIdx.x;             // 512 blocks
    const int nbid = ((bid & 7) << 6) + (bid >> 3);   // XCD chunking: 1 image/XCD
    const int b    = nbid >> 6;
    const int row  = nbid & 63;

    const int t  = threadIdx.x;
    const int s  = t & 63;                   // position in row
    const int wv = t >> 6;                   // channel quarter 0..3
    const int wvu = __builtin_amdgcn_readfirstlane(wv);

    float m[K2_]; int idx[K2_];
#pragma unroll
    for (int ky = 0; ky < 3; ++ky) {
#pragma unroll
        for (int kx = 0; kx < 3; ++kx) {
            int y  = row - 1 + ky;
            int xx = s  - 1 + kx;
            bool v = (y >= 0) & (y < H_) & (xx >= 0) & (xx < W_);
            int yc = min(max(y, 0), H_ - 1);
            int xc = min(max(xx, 0), W_ - 1);
            m[ky*3+kx]   = v ? 1.0f : 0.0f;
            idx[ky*3+kx] = yc * W_ + xc;
        }
    }

    const float* xb = x + ((size_t)b << 19) + ((size_t)wvu << 17);
    const float* wb = w_off + wvu * 32 * K2_;

    float acc[JOFF_];
#pragma unroll
    for (int j = 0; j < JOFF_; ++j) acc[j] = 0.f;

    for (int c = 0; c < 32; ++c) {
        const float* xc = xb + (c << 12);
        float xv[K2_];
#pragma unroll
        for (int k = 0; k < K2_; ++k) xv[k] = xc[idx[k]] * m[k];
#pragma unroll
        for (int k = 0; k < K2_; ++k) {
            const float* wp = wb + c * K2_ + k;
#pragma unroll
            for (int j = 0; j < JOFF_; ++j)
                acc[j] = fmaf(wp[(size_t)j * CK_], xv[k], acc[j]);
        }
    }

    if (wv > 0) {
#pragma unroll
        for (int j = 0; j < JOFF_; ++j) red[wv-1][j][s] = acc[j];
    }
    __syncthreads();
    if (wv == 0) {
#pragma unroll
        for (int j = 0; j < JOFF_; ++j) {
            float r = acc[j] + red[0][j][s] + red[1][j][s] + red[2][j][s] + b_off[j];
            offs[((size_t)(b * JOFF_ + j) << 12) + (row << 6) + s] = r;
        }
    }
}

// ---------------------------------------------------------------------------
// Kernel T: w_def -> wt[k][o][c ^ ((o&7)<<3)] bf16 (tap-major, PRE-SWIZZLED).
// The GEMM stages each tap tile into LDS with a LINEAR global_load_lds copy;
// the pre-swizzle makes ds_read_b128 fragment reads bank-conflict-free.
// ---------------------------------------------------------------------------
__global__ __launch_bounds__(256) void transpose_wdef_kernel(
    const float* __restrict__ w_def, ushort* __restrict__ wt)
{
    int t = blockIdx.x * 256 + threadIdx.x;
    if (t >= K2_ * COUT_ * C_) return;
    int c = t & 127;
    int o = (t >> 7) & 127;
    int k = t >> 14;
    float v = w_def[((size_t)o * C_ + c) * K2_ + k];
    wt[((size_t)k * COUT_ + o) * C_ + (c ^ ((o & 7) << 3))] = f2bf(v);
}

// ---------------------------------------------------------------------------
// Kernel B: fused deformable gather + MFMA GEMM.
// Block = 512 threads (8 waves, 2M x 4N wave grid), tile = 128 out-ch x 64
// positions (one image row). Per tap:
//   issue sA DMA (global_load_lds, pre-swizzled wt) -> gather B tile ->
//   barrier (drains DMA + ds_writes) -> MFMA from LDS -> barrier.
// ---------------------------------------------------------------------------
__global__ __launch_bounds__(512, 4) void deform_mfma_kernel(
    const float* __restrict__ x, const float* __restrict__ offs,
    const ushort* __restrict__ wt, float* __restrict__ out)
{
    __shared__ ushort sA[COUT_][C_];         // 32 KB, pre-swizzled tap tile
    __shared__ ushort sB[64][C_];            // 16 KB, XOR-swizzled gather tile
    __shared__ float  s_off[JOFF_][64];      // 4.6 KB raw offsets for this row

    const int bid  = blockIdx.x;             // 512 blocks
    const int nbid = ((bid & 7) << 6) + (bid >> 3);   // XCD chunking: 1 image/XCD
    const int s0   = nbid << 6;
    const int b    = s0 >> 12;
    const int hw0  = s0 & (HW_ - 1);
    const int ho   = hw0 >> 6;

    const int t    = threadIdx.x;
    const int wid  = t >> 6, lane = t & 63;
    const int wm   = wid >> 2, wn = wid & 3; // 2x4 wave grid: 64(M) x 16(N)
    const int sg   = lane;                   // gather position = lane
    const float* xb = x + ((size_t)b << 19);

    // Phase 0: cache this row's 18 offset planes in LDS (coalesced)
    for (int e = t; e < JOFF_ * 64; e += 512) {
        int j = e >> 6, s = e & 63;
        s_off[j][s] = offs[((size_t)(b * JOFF_ + j) << 12) + hw0 + s];
    }
    __syncthreads();

    f32x4 acc[4] = {};
    const int swz  = (sg & 7) << 3;
    const int arow = lane & 15;
    const int akk  = (lane >> 4) << 3;
    ushort* sAlin = &sA[0][0];

    for (int k = 0; k < K2_; ++k) {
        // ---- issue A-tile DMA: 32 KB linear copy, 4 rounds x 512 thr x 16 B.
        // LDS dest = wave-uniform base + lane*16 (hardware); global src per-lane.
        {
            const ushort* src = wt + (size_t)k * (COUT_ * C_);
#pragma unroll
            for (int i = 0; i < 4; ++i) {
                int off = i * 4096 + wid * 512;          // ushort offset of wave chunk
                gl2lds16(src + off + lane * 8, sAlin + off);
            }
        }

        // ---- bilinear setup for this lane's position (registers only)
        float dy = s_off[2*k    ][sg];
        float dx = s_off[2*k + 1][sg];
        float py = (float)(ho - 1 + k/3) + dy;
        float px = (float)(sg - 1 + k%3) + dx;
        float y0f = floorf(py), x0f = floorf(px);
        float wy = py - y0f,    wx = px - x0f;
        int y0 = (int)y0f, x0 = (int)x0f;
        int y1 = y0 + 1,   x1 = x0 + 1;
        float vy0 = (y0 >= 0 && y0 < H_) ? 1.f : 0.f;
        float vy1 = (y1 >= 0 && y1 < H_) ? 1.f : 0.f;
        float vx0 = (x0 >= 0 && x0 < W_) ? 1.f : 0.f;
        float vx1 = (x1 >= 0 && x1 < W_) ? 1.f : 0.f;
        int y0c = min(max(y0, 0), H_-1), y1c = min(max(y1, 0), H_-1);
        int x0c = min(max(x0, 0), W_-1), x1c = min(max(x1, 0), W_-1);
        float wr[4]; int ixr[4];
        wr[0] = (1.f-wy)*(1.f-wx)*vy0*vx0;  ixr[0] = y0c*W_ + x0c;
        wr[1] = (1.f-wy)*wx      *vy0*vx1;  ixr[1] = y0c*W_ + x1c;
        wr[2] = wy      *(1.f-wx)*vy1*vx0;  ixr[2] = y1c*W_ + x0c;
        wr[3] = wy      *wx      *vy1*vx1;  ixr[3] = y1c*W_ + x1c;

        // ---- gather B tile: 4 channels per iter, one ds_write_b64
#pragma unroll
        for (int i = 0; i < 4; ++i) {
            int c0 = (wid + i*8) * 4;                // channels c0..c0+3
            const float* xc0 = xb + ((size_t)c0 << 12);
            float v0 = 0.f, v1 = 0.f, v2 = 0.f, v3 = 0.f;
#pragma unroll
            for (int r = 0; r < 4; ++r) {
                v0 = fmaf(wr[r], xc0[ixr[r]          ], v0);
                v1 = fmaf(wr[r], xc0[ixr[r] +   HW_  ], v1);
                v2 = fmaf(wr[r], xc0[ixr[r] + 2*HW_  ], v2);
                v3 = fmaf(wr[r], xc0[ixr[r] + 3*HW_  ], v3);
            }
            uint pk0 = (uint)f2bf(v0) | ((uint)f2bf(v1) << 16);
            uint pk1 = (uint)f2bf(v2) | ((uint)f2bf(v3) << 16);
            uint2 pk = make_uint2(pk0, pk1);
            *reinterpret_cast<uint2*>(&sB[sg][c0 ^ swz]) = pk;
        }
        __syncthreads();   // drains sA DMA (vmcnt) + sB writes (lgkmcnt)

        // ---- MFMA: 4 chunks of K=32 channels, A and B from LDS
#pragma unroll
        for (int kc = 0; kc < 4; ++kc) {
            const int kk = kc*32 + akk;
            short8 aF[4], bF;
            {
                int srow = wn*16 + (lane & 15);
                bF = *reinterpret_cast<const short8*>(
                    &sB[srow][kk ^ ((srow & 7) << 3)]);
            }
#pragma unroll
            for (int mi = 0; mi < 4; ++mi) {
                int o = wm*64 + mi*16 + arow;
                aF[mi] = *reinterpret_cast<const short8*>(
                    &sA[o][kk ^ ((o & 7) << 3)]);
            }
#pragma unroll
            for (int mi = 0; mi < 4; ++mi)
                acc[mi] = __builtin_amdgcn_mfma_f32_16x16x32_bf16(
                    aF[mi], bF, acc[mi], 0, 0, 0);
        }
        __syncthreads();   // protect next tap's sA/sB overwrite
    }

    // ---- epilogue: C/D layout col=lane&15, row=(lane>>4)*4+reg; nt stores
#pragma unroll
    for (int mi = 0; mi < 4; ++mi) {
#pragma unroll
        for (int r = 0; r < 4; ++r) {
            int o = wm*64 + mi*16 + ((lane >> 4) * 4 + r);
            int s = wn*16 + (lane & 15);
            __builtin_nontemporal_store(acc[mi][r],
                &out[(((size_t)(b*COUT_ + o)) << 12) + hw0 + s]);
        }
    }
}

// ---------------------------------------------------------------------------
extern "C" void kernel_launch(void* const* d_in, const int* in_sizes, int n_in,
                              void* d_out, int out_size, void* d_ws, size_t ws_size,
                              hipStream_t stream) {
    const float* x     = (const float*)d_in[0];
    const float* w_off = (const float*)d_in[1];
    const float* b_off = (const float*)d_in[2];
    const float* w_def = (const float*)d_in[3];
    float* out  = (float*)d_out;

    float*  offs = (float*)d_ws;                                    // 2,359,296 B
    ushort* wt   = (ushort*)((char*)d_ws + (size_t)B_*JOFF_*HW_*4); //   294,912 B

    // Kernel A: offsets (one block per (b,row))
    {
        offset_conv_kernel<<<B_ * H_, 256, 0, stream>>>(x, w_off, b_off, offs);
    }
    // Kernel T: w_def -> bf16 tap-major, pre-swizzled
    {
        int total  = K2_ * COUT_ * C_;
        int blocks = (total + 255) / 256;
        transpose_wdef_kernel<<<blocks, 256, 0, stream>>>(w_def, wt);
    }
    // Kernel B: fused gather + MFMA GEMM
    {
        int blocks = (B_ * HW_) / 64;   // 512
        deform_mfma_kernel<<<blocks, 512, 0, stream>>>(x, offs, wt, out);
    }
}